// Round 2
// baseline (1101.317 us; speedup 1.0000x reference)
//
#include <hip/hip_runtime.h>
#include <math.h>

// Problem constants (from reference):
//   N=131072 rows, INPT_DIM=128, output labels = argmin_k ||c1_k||^2 - 2*x.c1_k
//   where x = inpt[:, 64:128], centers1 shape (1024, 64). centers0 unused.
constexpr int N_ROWS   = 131072;
constexpr int INPT_DIM = 128;
constexpr int DIM      = 64;     // slice width (second slice)
constexpr int COL_OFF  = 64;     // offset of second slice
constexpr int NCENT    = 1024;

// ---------------------------------------------------------------------------
// Kernel 1: per-center squared norms, f64 (exact path) and f32 (fast path).
// ---------------------------------------------------------------------------
__global__ void cnorm_kernel(const float* __restrict__ centers,
                             double* __restrict__ cnorm_d,
                             float* __restrict__ cnorm_f) {
    int k = blockIdx.x * blockDim.x + threadIdx.x;
    if (k >= NCENT) return;
    const float* c = centers + (size_t)k * DIM;
    double sd = 0.0;
#pragma unroll 8
    for (int d = 0; d < DIM; ++d) {
        double cd = (double)c[d];
        sd = fma(cd, cd, sd);
    }
    cnorm_d[k] = sd;
    cnorm_f[k] = (float)sd;
}

// ---------------------------------------------------------------------------
// Kernel 2: one thread per row; 8 centers per k-iteration.
// R1 post-mortem: VGPR_Count=52 proved x[64] was NOT register-resident
// (allocator capped regs for occupancy the 2048-wave grid can't use) ->
// 4.4x VALU inflation. __launch_bounds__(256, 2) raises the cap to 256
// VGPRs/wave; grid supplies 2 waves/SIMD either way.
// ---------------------------------------------------------------------------
__device__ __forceinline__ double exact_score(const float* __restrict__ c,
                                              const float x[DIM], double cn) {
    double acc = 0.0;
#pragma unroll
    for (int d = 0; d < DIM; ++d)
        acc = fma((double)c[d], (double)x[d], acc);
    return fma(-2.0, acc, cn);
}

__launch_bounds__(256, 2)
__global__ void label_kernel(const float* __restrict__ inpt,
                             const float* __restrict__ centers,
                             const double* __restrict__ cnorm_d,
                             const float* __restrict__ cnorm_f,
                             int* __restrict__ out) {
    int row = blockIdx.x * blockDim.x + threadIdx.x;
    if (row >= N_ROWS) return;

    // This row's 64-wide slice -> registers (fully unrolled float4 loads).
    const float* xr = inpt + (size_t)row * INPT_DIM + COL_OFF;
    float x[DIM];
#pragma unroll
    for (int d = 0; d < DIM; d += 4) {
        float4 v = *reinterpret_cast<const float4*>(xr + d);
        x[d] = v.x; x[d + 1] = v.y; x[d + 2] = v.z; x[d + 3] = v.w;
    }

    float min1 = INFINITY, min2 = INFINITY;
    int arg1 = 0, arg2 = 0;

    // 8 centers per iteration: 512 independent FMAs per iter, center data is
    // wave-uniform -> scalar (s_load) operands feeding v_fma_f32 directly.
    for (int k = 0; k < NCENT; k += 8) {
        const float* c = centers + (size_t)k * DIM;
        float acc[8];
#pragma unroll
        for (int j = 0; j < 8; ++j) acc[j] = 0.f;

        // d-chunks of 16 keep live scalar c-values bounded for the SGPR file.
#pragma unroll
        for (int dc = 0; dc < DIM; dc += 16) {
#pragma unroll
            for (int j = 0; j < 8; ++j) {
#pragma unroll
                for (int d = 0; d < 16; ++d) {
                    acc[j] = fmaf(c[j * DIM + dc + d], x[dc + d], acc[j]);
                }
            }
        }

#pragma unroll
        for (int j = 0; j < 8; ++j) {
            float s = fmaf(-2.f, acc[j], cnorm_f[k + j]);
            // Ascending-k sequential top-2: strict < keeps first-min index.
            if (s < min1) { min2 = min1; arg2 = arg1; min1 = s; arg1 = k + j; }
            else if (s < min2) { min2 = s; arg2 = k + j; }
        }
    }

    int result = arg1;
    // fp32 worst-case score error ~1e-4 here; 2e-3 gap is decisive.
    if (min2 - min1 < 2.0e-3f) {
        double e1 = exact_score(centers + (size_t)arg1 * DIM, x, cnorm_d[arg1]);
        double e2 = exact_score(centers + (size_t)arg2 * DIM, x, cnorm_d[arg2]);
        if (e2 < e1 || (e2 == e1 && arg2 < arg1)) result = arg2;
    }
    out[row] = result;
}

// ---------------------------------------------------------------------------
extern "C" void kernel_launch(void* const* d_in, const int* in_sizes, int n_in,
                              void* d_out, int out_size, void* d_ws, size_t ws_size,
                              hipStream_t stream) {
    const float* inpt     = (const float*)d_in[0];
    // d_in[1] = centers0 — unused (reference returns last slice's labels only)
    const float* centers1 = (const float*)d_in[2];
    int* out = (int*)d_out;

    // Workspace layout: [0, 8K) f64 cnorm, [8K, 12K) f32 cnorm.
    double* cnorm_d = (double*)d_ws;
    float*  cnorm_f = (float*)((char*)d_ws + NCENT * sizeof(double));

    cnorm_kernel<<<(NCENT + 255) / 256, 256, 0, stream>>>(centers1, cnorm_d, cnorm_f);
    label_kernel<<<N_ROWS / 256, 256, 0, stream>>>(inpt, centers1, cnorm_d, cnorm_f, out);
}

// Round 3
// 281.756 us; speedup vs baseline: 3.9088x; 3.9088x over previous
//
#include <hip/hip_runtime.h>
#include <math.h>

// Problem: labels = argmin_k ||c1_k||^2 - 2*x.c1_k, x = inpt[:,64:128] (131072x64),
// centers1 (1024x64). centers0 unused. Output int32 labels.
constexpr int N_ROWS   = 131072;
constexpr int INPT_DIM = 128;
constexpr int DIM      = 64;
constexpr int COL_OFF  = 64;
constexpr int NCENT    = 1024;

constexpr int TM     = 64;            // rows per block
constexpr int CHUNK  = 64;            // centers per chunk
constexpr int NCHUNK = NCENT / CHUNK; // 16
constexpr int MAXC   = 32;            // candidate list capacity per row

typedef short short8 __attribute__((ext_vector_type(8)));
typedef float f32x4  __attribute__((ext_vector_type(4)));

// ws layout:
//   [0,      8192): double cnorm_d[1024]
//   [8192,  12288): float  cnorm_f[1024]
//   [12288, 12292): float  maxC
//   [16384, 147456): unsigned short cbf[1024][64]  (bf16 centers)

__device__ __forceinline__ unsigned short f2bf(float f) {
    unsigned u = __float_as_uint(f);
    u += 0x7fff + ((u >> 16) & 1);          // round-to-nearest-even
    return (unsigned short)(u >> 16);
}

__device__ __forceinline__ double exact_score(const float* __restrict__ c,
                                              const float* __restrict__ x, double cn) {
    double acc = 0.0;
#pragma unroll
    for (int d = 0; d < DIM; ++d)
        acc = fma((double)c[d], (double)x[d], acc);
    return fma(-2.0, acc, cn);
}

// ---------------------------------------------------------------------------
// Prep: bf16 centers + f64/f32 norms + max ||c||. One block of 1024 threads.
// ---------------------------------------------------------------------------
__global__ __launch_bounds__(1024) void prep_kernel(const float* __restrict__ centers,
                                                    double* __restrict__ cnorm_d,
                                                    float* __restrict__ cnorm_f,
                                                    float* __restrict__ maxc,
                                                    unsigned short* __restrict__ cbf) {
    int k = threadIdx.x;
    const float* c = centers + (size_t)k * DIM;
    unsigned short* cb = cbf + (size_t)k * DIM;
    double sd = 0.0;
#pragma unroll
    for (int d = 0; d < DIM; d += 4) {
        float4 v = *reinterpret_cast<const float4*>(c + d);
        sd = fma((double)v.x, (double)v.x, sd);
        sd = fma((double)v.y, (double)v.y, sd);
        sd = fma((double)v.z, (double)v.z, sd);
        sd = fma((double)v.w, (double)v.w, sd);
        unsigned u0 = (unsigned)f2bf(v.x) | ((unsigned)f2bf(v.y) << 16);
        unsigned u1 = (unsigned)f2bf(v.z) | ((unsigned)f2bf(v.w) << 16);
        *reinterpret_cast<unsigned*>(cb + d)     = u0;
        *reinterpret_cast<unsigned*>(cb + d + 2) = u1;
    }
    cnorm_d[k] = sd;
    cnorm_f[k] = (float)sd;
    __shared__ float red[1024];
    red[k] = sqrtf((float)sd);
    __syncthreads();
    for (int s = 512; s > 0; s >>= 1) {
        if (k < s) red[k] = fmaxf(red[k], red[k + s]);
        __syncthreads();
    }
    if (k == 0) maxc[0] = red[0];
}

// ---------------------------------------------------------------------------
// Main: 64 rows/block, bf16 MFMA screening + margin candidates + f64 resolve.
// ---------------------------------------------------------------------------
__global__ __launch_bounds__(256) void label_kernel(
        const float* __restrict__ inpt, const float* __restrict__ centers,
        const double* __restrict__ cnorm_d, const float* __restrict__ cnorm_f,
        const float* __restrict__ maxc_p, const unsigned short* __restrict__ cbf,
        int* __restrict__ out) {
    // 144-byte rows (72 bf16): b128 frag reads land 8 lanes per 4-bank group
    // (the LDS-BW floor); 64-bf16 rows would be 16-way. 69-float score rows:
    // 2-way on scan loads (free), <=3-way on stores.
    __shared__ unsigned short A_lds[TM][72];
    __shared__ unsigned short B_lds[CHUNK][72];
    __shared__ float S_lds[TM][69];
    __shared__ float stripmin[TM][4];
    __shared__ float runmin[TM];
    __shared__ float margin[TM];
    __shared__ int   cand[TM][MAXC];
    __shared__ int   ccount[TM];

    const int tid  = threadIdx.x;
    const int lane = tid & 63;
    const int wave = tid >> 6;
    const int rowBase = blockIdx.x * TM;

    // ---- stage x slice -> bf16 LDS, accumulate |x|^2 partials
    {
        int r = tid >> 2, kq = tid & 3;
        const float* xp = inpt + (size_t)(rowBase + r) * INPT_DIM + COL_OFF + kq * 16;
        float ss = 0.f;
#pragma unroll
        for (int j = 0; j < 4; ++j) {
            float4 v = *reinterpret_cast<const float4*>(xp + j * 4);
            ss = fmaf(v.x, v.x, fmaf(v.y, v.y, fmaf(v.z, v.z, fmaf(v.w, v.w, ss))));
            unsigned u0 = (unsigned)f2bf(v.x) | ((unsigned)f2bf(v.y) << 16);
            unsigned u1 = (unsigned)f2bf(v.z) | ((unsigned)f2bf(v.w) << 16);
            *reinterpret_cast<unsigned*>(&A_lds[r][kq * 16 + j * 4])     = u0;
            *reinterpret_cast<unsigned*>(&A_lds[r][kq * 16 + j * 4 + 2]) = u1;
        }
        stripmin[r][kq] = ss;   // reuse as |x|^2 partial buffer pre-loop
    }
    __syncthreads();
    if (tid < TM) {
        float nx2 = stripmin[tid][0] + stripmin[tid][1] + stripmin[tid][2] + stripmin[tid][3];
        // score err <= 2^-7*|x|*|c| (RN bf16, Cauchy-Schwarz); margin = 1.5 * 2*eps
        margin[tid] = (1.5f / 64.f) * sqrtf(nx2) * maxc_p[0] + 1e-3f;
        runmin[tid] = INFINITY;
        ccount[tid] = 0;
    }
    __syncthreads();

    // ---- persistent A fragments (verified m89 layout: A[m=lane&15][k=q*8+j])
    const int m = lane & 15, q = lane >> 4;
    const short8 afrag0 = *reinterpret_cast<const short8*>(&A_lds[wave * 16 + m][q * 8]);
    const short8 afrag1 = *reinterpret_cast<const short8*>(&A_lds[wave * 16 + m][32 + q * 8]);

    for (int ch = 0; ch < NCHUNK; ++ch) {
        // stage B chunk (64 centers x 64 k, bf16)
        {
            int n = tid >> 2, kq = tid & 3;
            const unsigned short* bp = cbf + (size_t)(ch * CHUNK + n) * DIM + kq * 16;
            uint4 w0 = *reinterpret_cast<const uint4*>(bp);
            uint4 w1 = *reinterpret_cast<const uint4*>(bp + 8);
            *reinterpret_cast<uint4*>(&B_lds[n][kq * 16])     = w0;
            *reinterpret_cast<uint4*>(&B_lds[n][kq * 16 + 8]) = w1;
        }
        __syncthreads();  // B ready; also orders prev-chunk scan reads vs S rewrite

#pragma unroll
        for (int mt = 0; mt < 4; ++mt) {
            short8 b0 = *reinterpret_cast<const short8*>(&B_lds[mt * 16 + m][q * 8]);
            short8 b1 = *reinterpret_cast<const short8*>(&B_lds[mt * 16 + m][32 + q * 8]);
            f32x4 acc = {0.f, 0.f, 0.f, 0.f};
            acc = __builtin_amdgcn_mfma_f32_16x16x32_bf16(afrag0, b0, acc, 0, 0, 0);
            acc = __builtin_amdgcn_mfma_f32_16x16x32_bf16(afrag1, b1, acc, 0, 0, 0);
            float cn = cnorm_f[ch * CHUNK + mt * 16 + m];
#pragma unroll
            for (int r4 = 0; r4 < 4; ++r4)   // D: col=lane&15, row=q*4+r4 (m89)
                S_lds[wave * 16 + q * 4 + r4][mt * 16 + m] = fmaf(-2.f, acc[r4], cn);
        }
        __syncthreads();  // scores ready

        // phase a: strip minima -> per-row running min (seeded before appends)
        {
            int r = tid >> 2, sub = tid & 3;
            float mn = INFINITY;
#pragma unroll
            for (int i = 0; i < 16; ++i) mn = fminf(mn, S_lds[r][sub * 16 + i]);
            stripmin[r][sub] = mn;
        }
        __syncthreads();
        if (tid < TM) {
            float mn = fminf(fminf(stripmin[tid][0], stripmin[tid][1]),
                             fminf(stripmin[tid][2], stripmin[tid][3]));
            runmin[tid] = fminf(runmin[tid], mn);
        }
        __syncthreads();
        // phase b: append candidates. runmin >= final min always => superset of
        // {s < final_min + margin} => exact argmin guaranteed in the list.
        {
            int r = tid >> 2, sub = tid & 3;
            float thresh = runmin[r] + margin[r];
#pragma unroll
            for (int i = 0; i < 16; ++i) {
                float s = S_lds[r][sub * 16 + i];
                if (s < thresh) {
                    int slot = atomicAdd(&ccount[r], 1);
                    if (slot < MAXC) cand[r][slot] = ch * CHUNK + sub * 16 + i;
                }
            }
        }
        // next iteration's first barrier orders phase-b reads vs S_lds rewrite
    }
    __syncthreads();

    // ---- exact f64 resolve, one thread per row
    if (tid < TM) {
        int r = tid;
        int cnt = ccount[r];
        int best;
        if (cnt == 1) {
            best = cand[r][0];
        } else {
            const float* xp = inpt + (size_t)(rowBase + r) * INPT_DIM + COL_OFF;
            double bestv = 1e300;
            best = 0x7fffffff;
            if (cnt <= MAXC) {
                for (int j = 0; j < cnt; ++j) {
                    int k = cand[r][j];
                    double s = exact_score(centers + (size_t)k * DIM, xp, cnorm_d[k]);
                    if (s < bestv || (s == bestv && k < best)) { bestv = s; best = k; }
                }
            } else {  // overflow fallback: full exact scan (P ~ 0)
                for (int k = 0; k < NCENT; ++k) {
                    double s = exact_score(centers + (size_t)k * DIM, xp, cnorm_d[k]);
                    if (s < bestv) { bestv = s; best = k; }  // ascending k: first-min kept
                }
            }
        }
        out[rowBase + r] = best;
    }
}

// ---------------------------------------------------------------------------
extern "C" void kernel_launch(void* const* d_in, const int* in_sizes, int n_in,
                              void* d_out, int out_size, void* d_ws, size_t ws_size,
                              hipStream_t stream) {
    const float* inpt     = (const float*)d_in[0];
    const float* centers1 = (const float*)d_in[2];   // centers0 (d_in[1]) unused
    int* out = (int*)d_out;

    char* ws = (char*)d_ws;
    double* cnorm_d = (double*)ws;
    float*  cnorm_f = (float*)(ws + 8192);
    float*  maxc    = (float*)(ws + 12288);
    unsigned short* cbf = (unsigned short*)(ws + 16384);

    prep_kernel<<<1, 1024, 0, stream>>>(centers1, cnorm_d, cnorm_f, maxc, cbf);
    label_kernel<<<N_ROWS / TM, 256, 0, stream>>>(inpt, centers1, cnorm_d, cnorm_f,
                                                  maxc, cbf, out);
}

// Round 4
// 232.459 us; speedup vs baseline: 4.7377x; 1.2121x over previous
//
#include <hip/hip_runtime.h>
#include <math.h>

// Problem: labels = argmin_k ||c1_k||^2 - 2*x.c1_k, x = inpt[:,64:128] (131072x64),
// centers1 (1024x64). centers0 unused. Output int32 labels.
constexpr int N_ROWS   = 131072;
constexpr int INPT_DIM = 128;
constexpr int DIM      = 64;
constexpr int COL_OFF  = 64;
constexpr int NCENT    = 1024;

constexpr int TM     = 64;            // rows per block
constexpr int CHUNK  = 64;            // centers per chunk
constexpr int NCHUNK = NCENT / CHUNK; // 16
constexpr int MAXC   = 32;            // candidate list capacity per row

typedef short short8 __attribute__((ext_vector_type(8)));
typedef float f32x4  __attribute__((ext_vector_type(4)));

// ws layout:
//   [0,      8192): double cnorm_d[1024]
//   [8192,  12288): float  cnorm_f[1024]
//   [12288, 12292): int    maxC (float bits, via atomicMax on positive floats)
//   [16384, 147456): unsigned short cbf[1024][64]  (bf16 centers)

__device__ __forceinline__ unsigned short f2bf(float f) {
    unsigned u = __float_as_uint(f);
    u += 0x7fff + ((u >> 16) & 1);          // round-to-nearest-even
    return (unsigned short)(u >> 16);
}

__device__ __forceinline__ double exact_score(const float* __restrict__ c,
                                              const float* __restrict__ x, double cn) {
    double acc = 0.0;
#pragma unroll
    for (int d = 0; d < DIM; ++d)
        acc = fma((double)c[d], (double)x[d], acc);
    return fma(-2.0, acc, cn);
}

// ---------------------------------------------------------------------------
// Prep: 16 blocks x 64 threads, one center each (R3's single block was ~90us,
// latency-bound on one CU). Wave-shuffle max + atomicMax on float-as-int
// (norms > 0 so int compare is monotone; 0xAA poison = negative int, loses).
// ---------------------------------------------------------------------------
__global__ __launch_bounds__(64) void prep_kernel(const float* __restrict__ centers,
                                                  double* __restrict__ cnorm_d,
                                                  float* __restrict__ cnorm_f,
                                                  int* __restrict__ maxc_i,
                                                  unsigned short* __restrict__ cbf) {
    int k = blockIdx.x * 64 + threadIdx.x;
    const float* c = centers + (size_t)k * DIM;
    unsigned short* cb = cbf + (size_t)k * DIM;
    double sd = 0.0;
#pragma unroll
    for (int d = 0; d < DIM; d += 4) {
        float4 v = *reinterpret_cast<const float4*>(c + d);
        sd = fma((double)v.x, (double)v.x, sd);
        sd = fma((double)v.y, (double)v.y, sd);
        sd = fma((double)v.z, (double)v.z, sd);
        sd = fma((double)v.w, (double)v.w, sd);
        unsigned u0 = (unsigned)f2bf(v.x) | ((unsigned)f2bf(v.y) << 16);
        unsigned u1 = (unsigned)f2bf(v.z) | ((unsigned)f2bf(v.w) << 16);
        *reinterpret_cast<unsigned*>(cb + d)     = u0;
        *reinterpret_cast<unsigned*>(cb + d + 2) = u1;
    }
    cnorm_d[k] = sd;
    cnorm_f[k] = (float)sd;
    float nm = sqrtf((float)sd);
#pragma unroll
    for (int mlane = 1; mlane < 64; mlane <<= 1)
        nm = fmaxf(nm, __shfl_xor(nm, mlane));
    if (threadIdx.x == 0) atomicMax(maxc_i, __float_as_int(nm));
}

// ---------------------------------------------------------------------------
// Main: 64 rows/block, bf16 MFMA screening with IN-REGISTER min/candidate
// tracking (R3 post-mortem: LDS score scan = 32 ds_read_b32 + 3 barriers per
// chunk -> MfmaUtil 3.5%, VALUBusy 12.5%, 1.75e7 bank-conflict cycles).
// D layout (m89): col=lane&15, row=(lane>>4)*4+reg. Lanes sharing q=lane>>4
// hold the same 4 rows -> 4-step shfl_xor min over the 16-lane group gives
// the per-row chunk min without touching LDS.
// ---------------------------------------------------------------------------
__global__ __launch_bounds__(256) void label_kernel(
        const float* __restrict__ inpt, const float* __restrict__ centers,
        const double* __restrict__ cnorm_d, const float* __restrict__ cnorm_f,
        const int* __restrict__ maxc_i, const unsigned short* __restrict__ cbf,
        int* __restrict__ out) {
    __shared__ unsigned short A_lds[TM][72];   // 144B rows: b128 frag reads
    __shared__ unsigned short B_lds[CHUNK][72];
    __shared__ float cn_lds[NCENT];
    __shared__ float nx2p[TM][4];
    __shared__ float margin[TM];
    __shared__ int   cand[TM][MAXC];
    __shared__ int   ccount[TM];

    const int tid  = threadIdx.x;
    const int lane = tid & 63;
    const int wave = tid >> 6;
    const int rowBase = blockIdx.x * TM;

    // ---- stage x slice -> bf16 LDS + |x|^2 partials
    {
        int r = tid >> 2, kq = tid & 3;
        const float* xp = inpt + (size_t)(rowBase + r) * INPT_DIM + COL_OFF + kq * 16;
        float ss = 0.f;
#pragma unroll
        for (int j = 0; j < 4; ++j) {
            float4 v = *reinterpret_cast<const float4*>(xp + j * 4);
            ss = fmaf(v.x, v.x, fmaf(v.y, v.y, fmaf(v.z, v.z, fmaf(v.w, v.w, ss))));
            unsigned u0 = (unsigned)f2bf(v.x) | ((unsigned)f2bf(v.y) << 16);
            unsigned u1 = (unsigned)f2bf(v.z) | ((unsigned)f2bf(v.w) << 16);
            *reinterpret_cast<unsigned*>(&A_lds[r][kq * 16 + j * 4])     = u0;
            *reinterpret_cast<unsigned*>(&A_lds[r][kq * 16 + j * 4 + 2]) = u1;
        }
        nx2p[r][kq] = ss;
    }
    // ---- stage cnorm_f -> LDS (256 threads x float4 = 1024)
    {
        float4 v = *reinterpret_cast<const float4*>(cnorm_f + tid * 4);
        *reinterpret_cast<float4*>(&cn_lds[tid * 4]) = v;
    }
    __syncthreads();
    if (tid < TM) {
        float nx2 = nx2p[tid][0] + nx2p[tid][1] + nx2p[tid][2] + nx2p[tid][3];
        // bf16 score err <= 2^-6 |x||c| (RN, Cauchy-Schwarz); same formula
        // that gave absmax=0 in R3.
        margin[tid] = (1.5f / 64.f) * sqrtf(nx2) * __int_as_float(maxc_i[0]) + 1e-3f;
        ccount[tid] = 0;
    }
    __syncthreads();

    // ---- persistent A fragments (m89: A[m=lane&15][k=(lane>>4)*8+j])
    const int m = lane & 15, q = lane >> 4;
    const short8 afrag0 = *reinterpret_cast<const short8*>(&A_lds[wave * 16 + m][q * 8]);
    const short8 afrag1 = *reinterpret_cast<const short8*>(&A_lds[wave * 16 + m][32 + q * 8]);

    float marg[4], rmin[4];
#pragma unroll
    for (int r4 = 0; r4 < 4; ++r4) {
        marg[r4] = margin[wave * 16 + q * 4 + r4];
        rmin[r4] = INFINITY;
    }

    for (int ch = 0; ch < NCHUNK; ++ch) {
        // stage B chunk (64 centers x 64 dims, bf16)
        {
            int n = tid >> 2, kq = tid & 3;
            const unsigned short* bp = cbf + (size_t)(ch * CHUNK + n) * DIM + kq * 16;
            uint4 w0 = *reinterpret_cast<const uint4*>(bp);
            uint4 w1 = *reinterpret_cast<const uint4*>(bp + 8);
            *reinterpret_cast<uint4*>(&B_lds[n][kq * 16])     = w0;
            *reinterpret_cast<uint4*>(&B_lds[n][kq * 16 + 8]) = w1;
        }
        __syncthreads();  // B ready

        f32x4 sc[4];
#pragma unroll
        for (int mt = 0; mt < 4; ++mt) {
            short8 b0 = *reinterpret_cast<const short8*>(&B_lds[mt * 16 + m][q * 8]);
            short8 b1 = *reinterpret_cast<const short8*>(&B_lds[mt * 16 + m][32 + q * 8]);
            f32x4 acc = {0.f, 0.f, 0.f, 0.f};
            acc = __builtin_amdgcn_mfma_f32_16x16x32_bf16(afrag0, b0, acc, 0, 0, 0);
            acc = __builtin_amdgcn_mfma_f32_16x16x32_bf16(afrag1, b1, acc, 0, 0, 0);
            float cn = cn_lds[ch * CHUNK + mt * 16 + m];
#pragma unroll
            for (int r4 = 0; r4 < 4; ++r4)
                sc[mt][r4] = fmaf(-2.f, acc[r4], cn);
        }
        __syncthreads();  // frag reads done; next chunk may restage B

        // per-row chunk min: 4 lane-local mins + 4-step shfl_xor over 16-lane group
#pragma unroll
        for (int r4 = 0; r4 < 4; ++r4) {
            float cm = fminf(fminf(sc[0][r4], sc[1][r4]), fminf(sc[2][r4], sc[3][r4]));
            cm = fminf(cm, __shfl_xor(cm, 1));
            cm = fminf(cm, __shfl_xor(cm, 2));
            cm = fminf(cm, __shfl_xor(cm, 4));
            cm = fminf(cm, __shfl_xor(cm, 8));
            rmin[r4] = fminf(rmin[r4], cm);
        }
        // candidate append: rmin >= final min always => superset of
        // {s < final_min + margin} => exact argmin guaranteed collected.
#pragma unroll
        for (int mt = 0; mt < 4; ++mt) {
#pragma unroll
            for (int r4 = 0; r4 < 4; ++r4) {
                if (sc[mt][r4] < rmin[r4] + marg[r4]) {
                    int rloc = wave * 16 + q * 4 + r4;
                    int slot = atomicAdd(&ccount[rloc], 1);
                    if (slot < MAXC) cand[rloc][slot] = ch * CHUNK + mt * 16 + m;
                }
            }
        }
    }
    __syncthreads();

    // ---- exact f64 resolve, one thread per row
    if (tid < TM) {
        int r = tid;
        int cnt = ccount[r];
        int best;
        if (cnt == 1) {
            best = cand[r][0];
        } else {
            const float* xp = inpt + (size_t)(rowBase + r) * INPT_DIM + COL_OFF;
            double bestv = 1e300;
            best = 0x7fffffff;
            if (cnt <= MAXC) {
                for (int j = 0; j < cnt; ++j) {
                    int k = cand[r][j];
                    double s = exact_score(centers + (size_t)k * DIM, xp, cnorm_d[k]);
                    if (s < bestv || (s == bestv && k < best)) { bestv = s; best = k; }
                }
            } else {  // overflow fallback: full exact scan (P ~ 0)
                for (int k = 0; k < NCENT; ++k) {
                    double s = exact_score(centers + (size_t)k * DIM, xp, cnorm_d[k]);
                    if (s < bestv) { bestv = s; best = k; }
                }
            }
        }
        out[rowBase + r] = best;
    }
}

// ---------------------------------------------------------------------------
extern "C" void kernel_launch(void* const* d_in, const int* in_sizes, int n_in,
                              void* d_out, int out_size, void* d_ws, size_t ws_size,
                              hipStream_t stream) {
    const float* inpt     = (const float*)d_in[0];
    const float* centers1 = (const float*)d_in[2];   // centers0 (d_in[1]) unused
    int* out = (int*)d_out;

    char* ws = (char*)d_ws;
    double* cnorm_d = (double*)ws;
    float*  cnorm_f = (float*)(ws + 8192);
    int*    maxc_i  = (int*)(ws + 12288);
    unsigned short* cbf = (unsigned short*)(ws + 16384);

    prep_kernel<<<NCENT / 64, 64, 0, stream>>>(centers1, cnorm_d, cnorm_f, maxc_i, cbf);
    label_kernel<<<N_ROWS / TM, 256, 0, stream>>>(inpt, centers1, cnorm_d, cnorm_f,
                                                  maxc_i, cbf, out);
}

// Round 5
// 172.007 us; speedup vs baseline: 6.4028x; 1.3515x over previous
//
#include <hip/hip_runtime.h>
#include <math.h>

// labels = argmin_k ||c1_k||^2 - 2*x.c1_k, x = inpt[:,64:128] (131072x64),
// centers1 (1024x64). centers0 unused. Output int32 labels.
constexpr int N_ROWS   = 131072;
constexpr int INPT_DIM = 128;
constexpr int DIM      = 64;
constexpr int COL_OFF  = 64;
constexpr int NCENT    = 1024;

constexpr int TM    = 64;           // rows per block (one wave, 4 A-frag sets)
constexpr int NTILE = NCENT / 16;   // 64 tiles of 16 centers
constexpr int MAXC  = 16;           // candidates/row (E~1.5 under final thresh)

typedef short short8 __attribute__((ext_vector_type(8)));
typedef float f32x4  __attribute__((ext_vector_type(4)));

// ws: [0,8192) f64 cnorm | [8192,12288) f32 cnorm | [12288,12292) maxC bits
//     [16384, 16384+131072) bf16 centers in MFMA-fragment-linear order:
//     frag (tile t, khalf f) lane l: 8 bf16 at ((t*2+f)*64 + l)*8
//     = centers[t*16 + (l&15)][f*32 + (l>>4)*8 + j]   (B[n][k], m89 layout)

__device__ __forceinline__ unsigned short f2bf(float f) {
    unsigned u = __float_as_uint(f);
    u += 0x7fff + ((u >> 16) & 1);          // round-to-nearest-even
    return (unsigned short)(u >> 16);
}

__device__ __forceinline__ double exact_score(const float* __restrict__ c,
                                              const float* __restrict__ x, double cn) {
    double acc = 0.0;
#pragma unroll
    for (int d = 0; d < DIM; ++d)
        acc = fma((double)c[d], (double)x[d], acc);
    return fma(-2.0, acc, cn);
}

// ---------------------------------------------------------------------------
// Prep: 16 blocks x 64 threads, one center each. Emits fragment-linear bf16
// so label_kernel B-loads are single coalesced dwordx4 (no LDS, no barriers).
// ---------------------------------------------------------------------------
__global__ __launch_bounds__(64) void prep_kernel(const float* __restrict__ centers,
                                                  double* __restrict__ cnorm_d,
                                                  float* __restrict__ cnorm_f,
                                                  int* __restrict__ maxc_i,
                                                  unsigned short* __restrict__ cbf) {
    int k = blockIdx.x * 64 + threadIdx.x;
    const float* c = centers + (size_t)k * DIM;
    float cf[DIM];
    double sd = 0.0;
#pragma unroll
    for (int d = 0; d < DIM; d += 4) {
        float4 v = *reinterpret_cast<const float4*>(c + d);
        cf[d] = v.x; cf[d + 1] = v.y; cf[d + 2] = v.z; cf[d + 3] = v.w;
        sd = fma((double)v.x, (double)v.x, sd);
        sd = fma((double)v.y, (double)v.y, sd);
        sd = fma((double)v.z, (double)v.z, sd);
        sd = fma((double)v.w, (double)v.w, sd);
    }
    cnorm_d[k] = sd;
    cnorm_f[k] = (float)sd;

    int t = k >> 4, n = k & 15;
#pragma unroll
    for (int f = 0; f < 2; ++f) {
#pragma unroll
        for (int qq = 0; qq < 4; ++qq) {
            const float* s = cf + f * 32 + qq * 8;
            uint4 w;
            w.x = (unsigned)f2bf(s[0]) | ((unsigned)f2bf(s[1]) << 16);
            w.y = (unsigned)f2bf(s[2]) | ((unsigned)f2bf(s[3]) << 16);
            w.z = (unsigned)f2bf(s[4]) | ((unsigned)f2bf(s[5]) << 16);
            w.w = (unsigned)f2bf(s[6]) | ((unsigned)f2bf(s[7]) << 16);
            *reinterpret_cast<uint4*>(cbf + ((size_t)((t * 2 + f) * 64 + qq * 16 + n)) * 8) = w;
        }
    }
    float nm = sqrtf((float)sd);
#pragma unroll
    for (int mk = 1; mk < 64; mk <<= 1)
        nm = fmaxf(nm, __shfl_xor(nm, mk));
    if (threadIdx.x == 0) atomicMax(maxc_i, __float_as_int(nm));  // 0xAA.. poison < 0, loses
}

// ---------------------------------------------------------------------------
// Main: one wave per block, 64 rows (4 A-frag sets). Barrier-free two-pass:
//   pass 1: stream 64 tiles, per-lane running min in regs (no cross-lane work)
//   one shfl reduction -> per-row threshold = rowmin + margin
//   pass 2: re-stream, append candidates < threshold (superset => exact)
// R4 post-mortem: 2 barriers + shfl chain + LDS per chunk = latency-bound
// (MfmaUtil 4%, VALUBusy 19%). This loop is loads+MFMA+fmin only.
// ---------------------------------------------------------------------------
__global__ __launch_bounds__(64) void label_kernel(
        const float* __restrict__ inpt, const float* __restrict__ centers,
        const double* __restrict__ cnorm_d, const float* __restrict__ cnorm_f,
        const int* __restrict__ maxc_i, const unsigned short* __restrict__ cbf,
        int* __restrict__ out) {
    __shared__ unsigned short A_lds[TM][72];   // 144B rows: frag reads <=2-way (free)
    __shared__ float cn_lds[NCENT];
    __shared__ float margin_lds[TM];
    __shared__ int   cand[TM][MAXC];
    __shared__ int   ccount[TM];

    const int lane = threadIdx.x;
    const int rowBase = blockIdx.x * TM;

    // ---- stage: lane r owns row r. |x|^2 is lane-local (no reduction needed).
    {
        const float* xp = inpt + (size_t)(rowBase + lane) * INPT_DIM + COL_OFF;
        float nx2 = 0.f;
#pragma unroll
        for (int d = 0; d < DIM; d += 4) {
            float4 v = *reinterpret_cast<const float4*>(xp + d);
            nx2 = fmaf(v.x, v.x, fmaf(v.y, v.y, fmaf(v.z, v.z, fmaf(v.w, v.w, nx2))));
            unsigned u0 = (unsigned)f2bf(v.x) | ((unsigned)f2bf(v.y) << 16);
            unsigned u1 = (unsigned)f2bf(v.z) | ((unsigned)f2bf(v.w) << 16);
            *reinterpret_cast<unsigned*>(&A_lds[lane][d])     = u0;
            *reinterpret_cast<unsigned*>(&A_lds[lane][d + 2]) = u1;
        }
        // bf16 score err <= 2^-7|x||c| each way; same formula as R3/R4 (absmax=0)
        margin_lds[lane] = (1.5f / 64.f) * sqrtf(nx2) * __int_as_float(maxc_i[0]) + 1e-3f;
        ccount[lane] = 0;
#pragma unroll
        for (int i = 0; i < 4; ++i) {
            int idx = i * 256 + lane * 4;
            *reinterpret_cast<float4*>(&cn_lds[idx]) =
                *reinterpret_cast<const float4*>(cnorm_f + idx);
        }
    }
    __syncthreads();

    const int m = lane & 15, q = lane >> 4;
    // A-frags (m89: A[m=lane&15][k=q*8+j]); 4 sets of 16 rows persist in VGPRs
    short8 af0[4], af1[4];
#pragma unroll
    for (int s = 0; s < 4; ++s) {
        af0[s] = *reinterpret_cast<const short8*>(&A_lds[s * 16 + m][q * 8]);
        af1[s] = *reinterpret_cast<const short8*>(&A_lds[s * 16 + m][32 + q * 8]);
    }

    const short8* bfrag = reinterpret_cast<const short8*>(cbf);

    // ---- pass 1: running min only
    float rmin[4][4];
#pragma unroll
    for (int s = 0; s < 4; ++s)
#pragma unroll
        for (int r4 = 0; r4 < 4; ++r4) rmin[s][r4] = INFINITY;

#pragma unroll 4
    for (int t = 0; t < NTILE; ++t) {
        short8 b0 = bfrag[(t * 2 + 0) * 64 + lane];
        short8 b1 = bfrag[(t * 2 + 1) * 64 + lane];
        float cn = cn_lds[t * 16 + m];
#pragma unroll
        for (int s = 0; s < 4; ++s) {
            f32x4 acc = {0.f, 0.f, 0.f, 0.f};
            acc = __builtin_amdgcn_mfma_f32_16x16x32_bf16(af0[s], b0, acc, 0, 0, 0);
            acc = __builtin_amdgcn_mfma_f32_16x16x32_bf16(af1[s], b1, acc, 0, 0, 0);
#pragma unroll
            for (int r4 = 0; r4 < 4; ++r4)   // D: col=m (center), row=q*4+r4 (x-row)
                rmin[s][r4] = fminf(rmin[s][r4], fmaf(-2.f, acc[r4], cn));
        }
    }

    // ---- one cross-lane reduction (16-lane m-groups) -> per-row thresholds
    float thresh[4][4], tmax[4];
    float tmax_all = -INFINITY;
#pragma unroll
    for (int s = 0; s < 4; ++s) {
        tmax[s] = -INFINITY;
#pragma unroll
        for (int r4 = 0; r4 < 4; ++r4) {
            float v = rmin[s][r4];
            v = fminf(v, __shfl_xor(v, 1));
            v = fminf(v, __shfl_xor(v, 2));
            v = fminf(v, __shfl_xor(v, 4));
            v = fminf(v, __shfl_xor(v, 8));
            v += margin_lds[s * 16 + q * 4 + r4];
            thresh[s][r4] = v;
            tmax[s] = fmaxf(tmax[s], v);
        }
        tmax_all = fmaxf(tmax_all, tmax[s]);
    }

    // ---- pass 2: recompute, append candidates under threshold
#pragma unroll 2
    for (int t = 0; t < NTILE; ++t) {
        short8 b0 = bfrag[(t * 2 + 0) * 64 + lane];
        short8 b1 = bfrag[(t * 2 + 1) * 64 + lane];
        float cn = cn_lds[t * 16 + m];
        f32x4 sc[4];
        float cmin = INFINITY;
#pragma unroll
        for (int s = 0; s < 4; ++s) {
            f32x4 acc = {0.f, 0.f, 0.f, 0.f};
            acc = __builtin_amdgcn_mfma_f32_16x16x32_bf16(af0[s], b0, acc, 0, 0, 0);
            acc = __builtin_amdgcn_mfma_f32_16x16x32_bf16(af1[s], b1, acc, 0, 0, 0);
#pragma unroll
            for (int r4 = 0; r4 < 4; ++r4) {
                sc[s][r4] = fmaf(-2.f, acc[r4], cn);
                cmin = fminf(cmin, sc[s][r4]);
            }
        }
        if (cmin < tmax_all) {            // rare (~1/3 of tiles): detailed checks
#pragma unroll
            for (int s = 0; s < 4; ++s) {
                float smin = fminf(fminf(sc[s][0], sc[s][1]), fminf(sc[s][2], sc[s][3]));
                if (smin < tmax[s]) {
#pragma unroll
                    for (int r4 = 0; r4 < 4; ++r4) {
                        if (sc[s][r4] < thresh[s][r4]) {
                            int row = s * 16 + q * 4 + r4;
                            int slot = atomicAdd(&ccount[row], 1);
                            if (slot < MAXC) cand[row][slot] = t * 16 + m;
                        }
                    }
                }
            }
        }
    }
    __syncthreads();

    // ---- exact f64 resolve: lane r resolves row r (argmin guaranteed in list)
    {
        int cnt = ccount[lane];
        int best;
        if (cnt == 1) {
            best = cand[lane][0];
        } else {
            const float* xp = inpt + (size_t)(rowBase + lane) * INPT_DIM + COL_OFF;
            double bestv = 1e300;
            best = 0x7fffffff;
            if (cnt <= MAXC) {
                for (int j = 0; j < cnt; ++j) {
                    int k = cand[lane][j];
                    double s = exact_score(centers + (size_t)k * DIM, xp, cnorm_d[k]);
                    if (s < bestv || (s == bestv && k < best)) { bestv = s; best = k; }
                }
            } else {  // overflow fallback: full exact scan (P ~ 0)
                for (int k = 0; k < NCENT; ++k) {
                    double s = exact_score(centers + (size_t)k * DIM, xp, cnorm_d[k]);
                    if (s < bestv) { bestv = s; best = k; }
                }
            }
        }
        out[rowBase + lane] = best;
    }
}

// ---------------------------------------------------------------------------
extern "C" void kernel_launch(void* const* d_in, const int* in_sizes, int n_in,
                              void* d_out, int out_size, void* d_ws, size_t ws_size,
                              hipStream_t stream) {
    const float* inpt     = (const float*)d_in[0];
    const float* centers1 = (const float*)d_in[2];   // centers0 (d_in[1]) unused
    int* out = (int*)d_out;

    char* ws = (char*)d_ws;
    double* cnorm_d = (double*)ws;
    float*  cnorm_f = (float*)(ws + 8192);
    int*    maxc_i  = (int*)(ws + 12288);
    unsigned short* cbf = (unsigned short*)(ws + 16384);

    prep_kernel<<<NCENT / 64, 64, 0, stream>>>(centers1, cnorm_d, cnorm_f, maxc_i, cbf);
    label_kernel<<<N_ROWS / TM, 64, 0, stream>>>(inpt, centers1, cnorm_d, cnorm_f,
                                                 maxc_i, cbf, out);
}

// Round 6
// 155.281 us; speedup vs baseline: 7.0924x; 1.1077x over previous
//
#include <hip/hip_runtime.h>
#include <math.h>

// labels = argmin_k ||c1_k||^2 - 2*x.c1_k, x = inpt[:,64:128] (131072x64),
// centers1 (1024x64). centers0 unused. Output int32 labels.
constexpr int N_ROWS   = 131072;
constexpr int INPT_DIM = 128;
constexpr int DIM      = 64;
constexpr int COL_OFF  = 64;
constexpr int NCENT    = 1024;

constexpr int TM    = 64;           // rows per block (one wave, 4 A-frag sets)
constexpr int NTILE = NCENT / 16;   // 64 tiles of 16 centers
constexpr int MAXC  = 16;           // candidates/row (E~1.5 under final thresh)

typedef short short8 __attribute__((ext_vector_type(8)));
typedef float f32x4  __attribute__((ext_vector_type(4)));

// ws: [0,8192) f64 cnorm | [8192,12288) f32 cnorm | [12288,12292) maxC bits
//     [16384, 16384+131072) bf16 centers, MFMA-fragment-linear:
//     frag (tile t, khalf f) lane l: 8 bf16 at ((t*2+f)*64 + l)*8
//     = centers[t*16 + (l&15)][f*32 + (l>>4)*8 + j]   (B[n][k], m89 layout)

__device__ __forceinline__ unsigned short f2bf(float f) {
    unsigned u = __float_as_uint(f);
    u += 0x7fff + ((u >> 16) & 1);          // round-to-nearest-even
    return (unsigned short)(u >> 16);
}

__device__ __forceinline__ double exact_score(const float* __restrict__ c,
                                              const float* __restrict__ x, double cn) {
    double acc = 0.0;
#pragma unroll
    for (int d = 0; d < DIM; ++d)
        acc = fma((double)c[d], (double)x[d], acc);
    return fma(-2.0, acc, cn);
}

// ---------------------------------------------------------------------------
// Prep v2: 4 threads per center (4096 threads, 16 blocks x 256). Each thread
// reads a contiguous 64B quarter-row (fully coalesced, vs R5's 256B-strided
// whole-row reads on 16 waves), shuffle-combines the norm over the 4 lanes,
// writes its 2 fragment-quads. R4/R5 deltas put old prep at ~15us.
// ---------------------------------------------------------------------------
__global__ __launch_bounds__(256) void prep_kernel(const float* __restrict__ centers,
                                                   double* __restrict__ cnorm_d,
                                                   float* __restrict__ cnorm_f,
                                                   int* __restrict__ maxc_i,
                                                   unsigned short* __restrict__ cbf) {
    int tid = blockIdx.x * 256 + threadIdx.x;   // 0..4095
    int k = tid >> 2, kq = tid & 3;             // center, quarter
    const float* c = centers + (size_t)k * DIM + kq * 16;
    float cf[16];
    double sd = 0.0;
#pragma unroll
    for (int j = 0; j < 4; ++j) {
        float4 v = *reinterpret_cast<const float4*>(c + j * 4);
        cf[j * 4] = v.x; cf[j * 4 + 1] = v.y; cf[j * 4 + 2] = v.z; cf[j * 4 + 3] = v.w;
        sd = fma((double)v.x, (double)v.x, sd);
        sd = fma((double)v.y, (double)v.y, sd);
        sd = fma((double)v.z, (double)v.z, sd);
        sd = fma((double)v.w, (double)v.w, sd);
    }
    // the 4 lanes of one center are adjacent (tid = k*4+kq): xor-combine norm
    sd += __shfl_xor(sd, 1);
    sd += __shfl_xor(sd, 2);
    if (kq == 0) { cnorm_d[k] = sd; cnorm_f[k] = (float)sd; }

    // dims [kq*16, kq*16+16) -> khalf f = kq>>1, quads qq = (kq&1)*2 + h
    int t = k >> 4, n = k & 15, f = kq >> 1;
#pragma unroll
    for (int h = 0; h < 2; ++h) {
        int qq = (kq & 1) * 2 + h;
        const float* s = cf + h * 8;
        uint4 w;
        w.x = (unsigned)f2bf(s[0]) | ((unsigned)f2bf(s[1]) << 16);
        w.y = (unsigned)f2bf(s[2]) | ((unsigned)f2bf(s[3]) << 16);
        w.z = (unsigned)f2bf(s[4]) | ((unsigned)f2bf(s[5]) << 16);
        w.w = (unsigned)f2bf(s[6]) | ((unsigned)f2bf(s[7]) << 16);
        *reinterpret_cast<uint4*>(cbf + ((size_t)((t * 2 + f) * 64 + qq * 16 + n)) * 8) = w;
    }
    float nm = sqrtf((float)sd);
#pragma unroll
    for (int mk = 1; mk < 64; mk <<= 1)
        nm = fmaxf(nm, __shfl_xor(nm, mk));
    if ((threadIdx.x & 63) == 0) atomicMax(maxc_i, __float_as_int(nm));  // poison<0 loses
}

// ---------------------------------------------------------------------------
// Main: one wave/block, 64 rows, barrier-free two-pass (R5 structure) plus
// explicit double-buffered register prefetch. R5 post-mortem: VGPR=92 ->
// no load pipelining -> ~900 cyc/tile of exposed L2 latency (m126: ~200 cyc).
// Here: compute 4 tiles while the next 4 tiles' frags+cn are in flight
// (~400 cyc distance); __launch_bounds__(64,2) gives the 256-VGPR budget.
// ---------------------------------------------------------------------------
__global__ __launch_bounds__(64, 2) void label_kernel(
        const float* __restrict__ inpt, const float* __restrict__ centers,
        const double* __restrict__ cnorm_d, const float* __restrict__ cnorm_f,
        const int* __restrict__ maxc_i, const unsigned short* __restrict__ cbf,
        int* __restrict__ out) {
    __shared__ unsigned short A_lds[TM][72];   // 144B rows: frag reads 2-way (free)
    __shared__ float cn_lds[NCENT];
    __shared__ float margin_lds[TM];
    __shared__ int   cand[TM][MAXC];
    __shared__ int   ccount[TM];

    const int lane = threadIdx.x;
    const int rowBase = blockIdx.x * TM;

    // ---- stage: lane r owns row r; |x|^2 lane-local
    {
        const float* xp = inpt + (size_t)(rowBase + lane) * INPT_DIM + COL_OFF;
        float nx2 = 0.f;
#pragma unroll
        for (int d = 0; d < DIM; d += 4) {
            float4 v = *reinterpret_cast<const float4*>(xp + d);
            nx2 = fmaf(v.x, v.x, fmaf(v.y, v.y, fmaf(v.z, v.z, fmaf(v.w, v.w, nx2))));
            unsigned u0 = (unsigned)f2bf(v.x) | ((unsigned)f2bf(v.y) << 16);
            unsigned u1 = (unsigned)f2bf(v.z) | ((unsigned)f2bf(v.w) << 16);
            *reinterpret_cast<unsigned*>(&A_lds[lane][d])     = u0;
            *reinterpret_cast<unsigned*>(&A_lds[lane][d + 2]) = u1;
        }
        // bf16 score err <= 2^-7|x||c| each way; formula unchanged since R3 (absmax=0)
        margin_lds[lane] = (1.5f / 64.f) * sqrtf(nx2) * __int_as_float(maxc_i[0]) + 1e-3f;
        ccount[lane] = 0;
#pragma unroll
        for (int i = 0; i < 4; ++i) {
            int idx = i * 256 + lane * 4;
            *reinterpret_cast<float4*>(&cn_lds[idx]) =
                *reinterpret_cast<const float4*>(cnorm_f + idx);
        }
    }
    __syncthreads();

    const int m = lane & 15, q = lane >> 4;
    short8 af0[4], af1[4];   // m89: A[m=lane&15][k=q*8+j]; 4 sets of 16 rows
#pragma unroll
    for (int s = 0; s < 4; ++s) {
        af0[s] = *reinterpret_cast<const short8*>(&A_lds[s * 16 + m][q * 8]);
        af1[s] = *reinterpret_cast<const short8*>(&A_lds[s * 16 + m][32 + q * 8]);
    }

    const short8* bfrag = reinterpret_cast<const short8*>(cbf);

    auto loadGroup = [&](short8 (&B0)[4], short8 (&B1)[4], float (&CN)[4], int tb) {
#pragma unroll
        for (int j = 0; j < 4; ++j) {
            B0[j] = bfrag[((tb + j) * 2 + 0) * 64 + lane];
            B1[j] = bfrag[((tb + j) * 2 + 1) * 64 + lane];
            CN[j] = cn_lds[(tb + j) * 16 + m];
        }
    };

    // ================= pass 1: running min only =================
    float rmin[4][4];
#pragma unroll
    for (int s = 0; s < 4; ++s)
#pragma unroll
        for (int r4 = 0; r4 < 4; ++r4) rmin[s][r4] = INFINITY;

    auto comp1 = [&](short8 (&B0)[4], short8 (&B1)[4], float (&CN)[4]) {
#pragma unroll
        for (int j = 0; j < 4; ++j) {
#pragma unroll
            for (int s = 0; s < 4; ++s) {
                f32x4 acc = {0.f, 0.f, 0.f, 0.f};
                acc = __builtin_amdgcn_mfma_f32_16x16x32_bf16(af0[s], B0[j], acc, 0, 0, 0);
                acc = __builtin_amdgcn_mfma_f32_16x16x32_bf16(af1[s], B1[j], acc, 0, 0, 0);
#pragma unroll
                for (int r4 = 0; r4 < 4; ++r4)   // D: col=m (center), row=q*4+r4
                    rmin[s][r4] = fminf(rmin[s][r4], fmaf(-2.f, acc[r4], CN[j]));
            }
        }
    };

    {
        short8 X0[4], X1[4], Y0[4], Y1[4];
        float  XC[4], YC[4];
        loadGroup(X0, X1, XC, 0);
        for (int gp = 0; gp < 8; ++gp) {          // dynamic loop: buffers stay regs
            int t0 = gp * 8;
            loadGroup(Y0, Y1, YC, t0 + 4);        // prefetch while computing X
            comp1(X0, X1, XC);
            if (gp < 7) loadGroup(X0, X1, XC, t0 + 8);
            comp1(Y0, Y1, YC);
        }
    }

    // ---- one cross-lane reduction (16-lane m-groups) -> per-row thresholds
    float thresh[4][4], tmax[4];
    float tmax_all = -INFINITY;
#pragma unroll
    for (int s = 0; s < 4; ++s) {
        tmax[s] = -INFINITY;
#pragma unroll
        for (int r4 = 0; r4 < 4; ++r4) {
            float v = rmin[s][r4];
            v = fminf(v, __shfl_xor(v, 1));
            v = fminf(v, __shfl_xor(v, 2));
            v = fminf(v, __shfl_xor(v, 4));
            v = fminf(v, __shfl_xor(v, 8));
            v += margin_lds[s * 16 + q * 4 + r4];
            thresh[s][r4] = v;
            tmax[s] = fmaxf(tmax[s], v);
        }
        tmax_all = fmaxf(tmax_all, tmax[s]);
    }

    // ================= pass 2: recompute + append candidates =================
    auto comp2 = [&](short8 (&B0)[4], short8 (&B1)[4], float (&CN)[4], int tb) {
#pragma unroll
        for (int j = 0; j < 4; ++j) {
            f32x4 sc[4];
            float cmin = INFINITY;
#pragma unroll
            for (int s = 0; s < 4; ++s) {
                f32x4 acc = {0.f, 0.f, 0.f, 0.f};
                acc = __builtin_amdgcn_mfma_f32_16x16x32_bf16(af0[s], B0[j], acc, 0, 0, 0);
                acc = __builtin_amdgcn_mfma_f32_16x16x32_bf16(af1[s], B1[j], acc, 0, 0, 0);
#pragma unroll
                for (int r4 = 0; r4 < 4; ++r4) {
                    sc[s][r4] = fmaf(-2.f, acc[r4], CN[j]);
                    cmin = fminf(cmin, sc[s][r4]);
                }
            }
            if (cmin < tmax_all) {
#pragma unroll
                for (int s = 0; s < 4; ++s) {
                    float smin = fminf(fminf(sc[s][0], sc[s][1]), fminf(sc[s][2], sc[s][3]));
                    if (smin < tmax[s]) {
#pragma unroll
                        for (int r4 = 0; r4 < 4; ++r4) {
                            if (sc[s][r4] < thresh[s][r4]) {   // pass1==pass2 scores (determinism)
                                int row = s * 16 + q * 4 + r4;
                                int slot = atomicAdd(&ccount[row], 1);
                                if (slot < MAXC) cand[row][slot] = (tb + j) * 16 + m;
                            }
                        }
                    }
                }
            }
        }
    };

    {
        short8 X0[4], X1[4], Y0[4], Y1[4];
        float  XC[4], YC[4];
        loadGroup(X0, X1, XC, 0);
        for (int gp = 0; gp < 8; ++gp) {
            int t0 = gp * 8;
            loadGroup(Y0, Y1, YC, t0 + 4);
            comp2(X0, X1, XC, t0);
            if (gp < 7) loadGroup(X0, X1, XC, t0 + 8);
            comp2(Y0, Y1, YC, t0 + 4);
        }
    }
    __syncthreads();

    // ---- exact f64 resolve: lane r resolves row r (argmin guaranteed in list)
    {
        int cnt = ccount[lane];
        int best;
        if (cnt == 1) {
            best = cand[lane][0];
        } else {
            const float* xp = inpt + (size_t)(rowBase + lane) * INPT_DIM + COL_OFF;
            double bestv = 1e300;
            best = 0x7fffffff;
            if (cnt <= MAXC) {
                for (int j = 0; j < cnt; ++j) {
                    int k = cand[lane][j];
                    double s = exact_score(centers + (size_t)k * DIM, xp, cnorm_d[k]);
                    if (s < bestv || (s == bestv && k < best)) { bestv = s; best = k; }
                }
            } else {  // overflow fallback: full exact scan (P ~ 0)
                for (int k = 0; k < NCENT; ++k) {
                    double s = exact_score(centers + (size_t)k * DIM, xp, cnorm_d[k]);
                    if (s < bestv) { bestv = s; best = k; }
                }
            }
        }
        out[rowBase + lane] = best;
    }
}

// ---------------------------------------------------------------------------
extern "C" void kernel_launch(void* const* d_in, const int* in_sizes, int n_in,
                              void* d_out, int out_size, void* d_ws, size_t ws_size,
                              hipStream_t stream) {
    const float* inpt     = (const float*)d_in[0];
    const float* centers1 = (const float*)d_in[2];   // centers0 (d_in[1]) unused
    int* out = (int*)d_out;

    char* ws = (char*)d_ws;
    double* cnorm_d = (double*)ws;
    float*  cnorm_f = (float*)(ws + 8192);
    int*    maxc_i  = (int*)(ws + 12288);
    unsigned short* cbf = (unsigned short*)(ws + 16384);

    prep_kernel<<<16, 256, 0, stream>>>(centers1, cnorm_d, cnorm_f, maxc_i, cbf);
    label_kernel<<<N_ROWS / TM, 64, 0, stream>>>(inpt, centers1, cnorm_d, cnorm_f,
                                                 maxc_i, cbf, out);
}